// Round 5
// baseline (780.085 us; speedup 1.0000x reference)
//
#include <hip/hip_runtime.h>
#include <hip/hip_bf16.h>
#include <math.h>

#define IHW 224
#define DIN 16
#define DOUT 8
#define HO 112
#define PO 56

typedef __bf16 bf16x8 __attribute__((ext_vector_type(8)));
typedef float f32x4 __attribute__((ext_vector_type(4)));
typedef float f32x16 __attribute__((ext_vector_type(16)));

__device__ __forceinline__ ushort f2bf(float f) {
  uint u = __float_as_uint(f);
  uint r = (u + 0x7FFFu + ((u >> 16) & 1u)) >> 16;
  return (ushort)r;
}
__device__ __forceinline__ float bf2f(ushort u) {
  return __uint_as_float(((uint)u) << 16);
}

// ---------------- weight prep: f32 [64][C][7][7][7] -> bf16 [oc][kd][kw][32] ----------------
// k32 = c*7+kh (zeros for k32 >= C*7)
template<int C>
__global__ __launch_bounds__(256) void wprep(const float* __restrict__ w, ushort* __restrict__ wB) {
  const int idx = blockIdx.x * 256 + threadIdx.x;
  if (idx >= 64 * 7 * 7 * 32) return;
  const int k  = idx & 31;
  const int kw = (idx >> 5) % 7;
  const int kd = (idx / 224) % 7;
  const int oc = idx / 1568;
  float val = 0.f;
  if (k < C * 7) {
    const int c = k / 7, kh = k % 7;
    val = w[(((oc * C + c) * 7 + kd) * 7 + kh) * 7 + kw];
  }
  wB[idx] = f2bf(val);
}

// ---------------- conv3d 7x7x7 s2 SAME + ReLU via bf16 MFMA, kd-sliced dbuf ----------------
// block = (ho, dd, b); out[b][0..63][dd][ho][0..111] (bf16)
// LDS buffer per kd: pair-rows [s>>1][128B], k=(c,kh) padded 32; XOR-swizzled granules
template<int C, typename Tin>
__global__ __launch_bounds__(256) void conv_mfma(
    const Tin* __restrict__ in, const ushort* __restrict__ wB,
    ushort* __restrict__ out)
{
  constexpr int CK = C * 7;
  constexpr int BUFB = 115 * 128;  // 14720 B per buffer
  __shared__ char smem[2 * BUFB];

  const int ho = blockIdx.x, dd = blockIdx.y, b = blockIdx.z;
  const int tid = threadIdx.x;
  const int lane = tid & 63, wv = tid >> 6;
  const int mhalf = wv >> 1, nhalf = wv & 1;
  const int row16 = lane & 15, ksub = lane >> 4;

  auto stage = [&](char* buf, int kd) {
    const int id = 2 * dd + kd - 2;
    const bool idok = (id >= 0) && (id < DIN);
    if (tid < 229) {
      const int iw = tid - 2;
      const bool wok = (iw >= 0) && (iw < IHW);
      const int prow = tid >> 1, podd = tid & 1, xr = prow & 7;
#pragma unroll
      for (int kg = 0; kg < 8; kg++) {
        ushort pk[4] = {0, 0, 0, 0};
#pragma unroll
        for (int j = 0; j < 4; j++) {
          const int k = kg * 4 + j;
          if (k < CK) {
            const int c = k / 7, kh = k % 7;
            const int ih = 2 * ho + kh - 2;
            if (idok && wok && ih >= 0 && ih < IHW) {
              const size_t off = (((size_t)(b * C + c) * DIN + id) * IHW + ih) * IHW + iw;
              if constexpr (sizeof(Tin) == 4) pk[j] = f2bf((float)in[off]);
              else pk[j] = (ushort)in[off];
            }
          }
        }
        const int gran = (podd * 4 + (kg >> 1)) ^ xr;
        *reinterpret_cast<ushort4*>(buf + prow * 128 + gran * 16 + (kg & 1) * 8) =
            make_ushort4(pk[0], pk[1], pk[2], pk[3]);
      }
    }
  };

  int s0[4];
#pragma unroll
  for (int mt = 0; mt < 4; mt++) {
    int ss = 2 * (mhalf * 64 + mt * 16 + row16);
    if (mhalf == 1 && mt == 3) ss -= 32;  // dead tile clamp (wo>=112)
    s0[mt] = ss;
  }
  const ushort* wq0 = wB + (size_t)(nhalf * 32 + row16) * (7 * 7 * 32) + ksub * 8;
  const ushort* wq1 = wq0 + (size_t)16 * (7 * 7 * 32);

  f32x4 acc[4][2] = {};

  stage(smem, 0);
  __syncthreads();
  for (int kd = 0; kd < 7; kd++) {
    char* cur = smem + (kd & 1) * BUFB;
    char* nxt = smem + ((kd + 1) & 1) * BUFB;
    if (kd < 6) stage(nxt, kd + 1);
    const ushort* wk0 = wq0 + kd * (7 * 32);
    const ushort* wk1 = wq1 + kd * (7 * 32);
#pragma unroll
    for (int kw = 0; kw < 7; kw++) {
      const bf16x8 b0 = *reinterpret_cast<const bf16x8*>(wk0 + kw * 32);
      const bf16x8 b1 = *reinterpret_cast<const bf16x8*>(wk1 + kw * 32);
#pragma unroll
      for (int mt = 0; mt < 4; mt++) {
        const int s = s0[mt] + kw;
        const int gran = ((s & 1) * 4 + ksub) ^ ((s >> 1) & 7);
        const bf16x8 a = *reinterpret_cast<const bf16x8*>(cur + (s >> 1) * 128 + gran * 16);
        acc[mt][0] = __builtin_amdgcn_mfma_f32_16x16x32_bf16(a, b0, acc[mt][0], 0, 0, 0);
        acc[mt][1] = __builtin_amdgcn_mfma_f32_16x16x32_bf16(a, b1, acc[mt][1], 0, 0, 0);
      }
    }
    __syncthreads();
  }

  // ---- epilogue: transpose via LDS (bf16), coalesced ushort4 stores ----
  ushort* eLDS = reinterpret_cast<ushort*>(smem);  // [64][116]
#pragma unroll
  for (int mt = 0; mt < 4; mt++) {
    const int wo_b = mhalf * 64 + mt * 16 + ksub * 4;
    if (wo_b < 112) {
#pragma unroll
      for (int n = 0; n < 2; n++) {
        const int oc = nhalf * 32 + n * 16 + row16;
        ushort4 r4;
        r4.x = f2bf(fmaxf(acc[mt][n][0], 0.f));
        r4.y = f2bf(fmaxf(acc[mt][n][1], 0.f));
        r4.z = f2bf(fmaxf(acc[mt][n][2], 0.f));
        r4.w = f2bf(fmaxf(acc[mt][n][3], 0.f));
        *reinterpret_cast<ushort4*>(eLDS + oc * 116 + wo_b) = r4;
      }
    }
  }
  __syncthreads();
  ushort* gout = out + ((size_t)(b * 64) * DOUT + dd) * (HO * HO) + ho * HO;
#pragma unroll
  for (int i = 0; i < 7; i++) {
    const int idx = i * 256 + tid;  // 0..1791 = 64 oc x 28 w4
    const int oc = idx / 28;
    const int w4 = idx - oc * 28;
    *reinterpret_cast<ushort4*>(gout + (size_t)oc * DOUT * (HO * HO) + w4 * 4) =
        *reinterpret_cast<const ushort4*>(eLDS + oc * 116 + w4 * 4);
  }
}

// ---------------- fused maxpool 3x3 s2 SAME + gather into GEMM X layout (bf16) ----------------
// bf16 max on raw bits is valid post-ReLU (all values >= 0)
__global__ void maxpool_gather(const ushort* __restrict__ in, ushort* __restrict__ X, int fbase) {
  const int idx = blockIdx.x * 256 + threadIdx.x;
  if (idx >= 2 * 64 * 8 * PO * PO) return;
  const int wo = idx % PO;
  const int ho = (idx / PO) % PO;
  const int rest = idx / (PO * PO);          // (b*64+c)*8+t
  const ushort* p = in + (size_t)rest * (HO * HO);
  ushort m = 0;
  for (int dh = 0; dh < 3; dh++) {
    const int ih = 2 * ho + dh;
    if (ih >= HO) break;
    for (int dw = 0; dw < 3; dw++) {
      const int iw = 2 * wo + dw;
      if (iw >= HO) break;
      const ushort v = p[ih * HO + iw];
      m = (v > m) ? v : m;
    }
  }
  const int t = rest % 8;
  const int c = (rest / 8) % 64;
  const int b = rest / 512;
  const int r = ((b * 8 + t) * 4 + ho / 14) * 4 + (wo / 14);
  const int f = fbase + c * 196 + (ho % 14) * 14 + (wo % 14);
  X[(size_t)r * 25088 + f] = m;
}

// ---------------- FCL1: X[256][25088] bf16 @ W1[25088][1024] f32(cvt in-kernel) ----------------
__global__ __launch_bounds__(512) void fcl1_mfma(
    const ushort* __restrict__ X, const float* __restrict__ W1, float* __restrict__ part)
{
  const int bn = blockIdx.x;
  const int kc = blockIdx.y;
  const int tid = threadIdx.x;
  const int lane = tid & 63;
  const int wv = tid >> 6;
  const int wm = wv >> 1, wn = wv & 1;
  const int l31 = lane & 31, kh = lane >> 5;

  __shared__ char xs[256 * 128];   // [r][64k] bf16, swz ((r&7)<<4)
  __shared__ char wsm[128 * 128];  // [n][64k] bf16, swz ((n&7)<<4)

  f32x16 acc[2][2] = {};

  const int kchunk0 = kc * 896;

  for (int kt = 0; kt < 14; kt++) {
    const int k0 = kchunk0 + kt * 64;
    __syncthreads();
#pragma unroll
    for (int i = 0; i < 4; i++) {
      const int chunk = tid + 512 * i;
      const int r = chunk >> 3, c8 = chunk & 7;
      const int4 v = *reinterpret_cast<const int4*>(X + (size_t)r * 25088 + k0 + c8 * 8);
      int byte = r * 128 + c8 * 16;
      byte ^= ((r & 7) << 4);
      *reinterpret_cast<int4*>(xs + byte) = v;
    }
    {
      const int nq = tid & 31, kp0 = tid >> 5;
#pragma unroll
      for (int h = 0; h < 2; h++) {
        const int kk = (kp0 + h * 16) * 2;
        const float4 a  = *reinterpret_cast<const float4*>(W1 + (size_t)(k0 + kk) * 1024 + bn * 128 + nq * 4);
        const float4 bq = *reinterpret_cast<const float4*>(W1 + (size_t)(k0 + kk + 1) * 1024 + bn * 128 + nq * 4);
        const float av[4] = {a.x, a.y, a.z, a.w};
        const float bv[4] = {bq.x, bq.y, bq.z, bq.w};
#pragma unroll
        for (int j = 0; j < 4; j++) {
          const int n = nq * 4 + j;
          const uint pack = (uint)f2bf(av[j]) | ((uint)f2bf(bv[j]) << 16);
          int byte = n * 128 + kk * 2;
          byte ^= ((n & 7) << 4);
          *reinterpret_cast<uint*>(wsm + byte) = pack;
        }
      }
    }
    __syncthreads();
#pragma unroll
    for (int ks = 0; ks < 4; ks++) {
      bf16x8 af[2], bfr[2];
#pragma unroll
      for (int m = 0; m < 2; m++) {
        const int r = wm * 64 + m * 32 + l31;
        const int byte = (r * 128 + ks * 32 + kh * 16) ^ ((r & 7) << 4);
        af[m] = *reinterpret_cast<const bf16x8*>(xs + byte);
      }
#pragma unroll
      for (int n = 0; n < 2; n++) {
        const int c = wn * 64 + n * 32 + l31;
        const int byte = (c * 128 + ks * 32 + kh * 16) ^ ((c & 7) << 4);
        bfr[n] = *reinterpret_cast<const bf16x8*>(wsm + byte);
      }
#pragma unroll
      for (int m = 0; m < 2; m++)
#pragma unroll
        for (int n = 0; n < 2; n++)
          acc[m][n] = __builtin_amdgcn_mfma_f32_32x32x16_bf16(af[m], bfr[n], acc[m][n], 0, 0, 0);
    }
  }

  float* pout = part + (size_t)kc * (256 * 1024);
#pragma unroll
  for (int m = 0; m < 2; m++)
#pragma unroll
    for (int n = 0; n < 2; n++)
#pragma unroll
      for (int rg = 0; rg < 16; rg++) {
        const int row = wm * 64 + m * 32 + (rg & 3) + 8 * (rg >> 2) + 4 * kh;
        const int col = bn * 128 + wn * 64 + n * 32 + l31;
        pout[(size_t)row * 1024 + col] = acc[m][n][rg];
      }
}

__global__ void h1_reduce(const float* __restrict__ part, const float* __restrict__ b1,
                          float* __restrict__ h1) {
  const int v = blockIdx.x * 256 + threadIdx.x;  // < 65536
  if (v >= 65536) return;
  const int n4 = v & 255;
  float4 s = *reinterpret_cast<const float4*>(b1 + n4 * 4);
  for (int kc = 0; kc < 28; kc++) {
    const float4 p = *reinterpret_cast<const float4*>(part + (size_t)kc * 262144 + v * 4);
    s.x += p.x; s.y += p.y; s.z += p.z; s.w += p.w;
  }
  const float4 r = make_float4(fmaxf(s.x, 0.f), fmaxf(s.y, 0.f), fmaxf(s.z, 0.f), fmaxf(s.w, 0.f));
  *reinterpret_cast<float4*>(h1 + v * 4) = r;
}

__global__ __launch_bounds__(256) void fcl2_k(const float* __restrict__ h1,
                                              const float* __restrict__ W2,
                                              const float* __restrict__ b2,
                                              float* __restrict__ h2) {
  const int r = blockIdx.x;
  const int n = threadIdx.x;
  __shared__ float xr[1024];
  for (int i = threadIdx.x; i < 1024; i += 256) xr[i] = h1[r * 1024 + i];
  __syncthreads();
  float s = b2[n];
  for (int k = 0; k < 1024; k++) s += xr[k] * W2[k * 256 + n];
  h2[r * 256 + n] = fmaxf(s, 0.f);
}

__global__ void fcl3_k(const float* __restrict__ h2, const float* __restrict__ W3,
                       const float* __restrict__ b3, float* __restrict__ ms) {
  __shared__ float w[256];
  w[threadIdx.x] = W3[threadIdx.x];
  __syncthreads();
  const int r = threadIdx.x;
  float s = b3[0];
  for (int k = 0; k < 256; k++) s += h2[r * 256 + k] * w[k];
  ms[r] = 1.f / (1.f + expf(-s));
}

__global__ void upsample_k(const float* __restrict__ ms, float* __restrict__ mask) {
  const int idx = blockIdx.x * 256 + threadIdx.x;
  if (idx >= 2 * 16 * IHW * IHW) return;
  const int w = idx % IHW;
  const int h = (idx / IHW) % IHW;
  const int t = (idx / (IHW * IHW)) % 16;
  const int b = idx / (16 * IHW * IHW);

  const float tf = t * 0.5f - 0.25f;
  const float hf = (h + 0.5f) * (1.f / 56.f) - 0.5f;
  const float wf = (w + 0.5f) * (1.f / 56.f) - 0.5f;

  int t0 = (int)floorf(tf); const float ft = tf - t0;
  int h0 = (int)floorf(hf); const float fh = hf - h0;
  int w0 = (int)floorf(wf); const float fw = wf - w0;
  const int t1 = min(t0 + 1, 7); t0 = max(t0, 0);
  const int h1 = min(h0 + 1, 3); h0 = max(h0, 0);
  const int w1 = min(w0 + 1, 3); w0 = max(w0, 0);

  const float* p = ms + b * 128;
  auto at = [&](int tt, int hh, int ww) { return p[(tt * 4 + hh) * 4 + ww]; };
  const float c00 = at(t0, h0, w0) * (1.f - fw) + at(t0, h0, w1) * fw;
  const float c01 = at(t0, h1, w0) * (1.f - fw) + at(t0, h1, w1) * fw;
  const float c10 = at(t1, h0, w0) * (1.f - fw) + at(t1, h0, w1) * fw;
  const float c11 = at(t1, h1, w0) * (1.f - fw) + at(t1, h1, w1) * fw;
  const float c0 = c00 * (1.f - fh) + c01 * fh;
  const float c1 = c10 * (1.f - fh) + c11 * fh;
  mask[idx] = c0 * (1.f - ft) + c1 * ft;
}

// masked = rgbs*m + bg*(1-m) -> bf16; flip -> m := 1-m
__global__ void masking_k(const float* __restrict__ rgbs, const float* __restrict__ mask,
                          const float* __restrict__ bg, ushort* __restrict__ out, int flip) {
  const int v = blockIdx.x * 256 + threadIdx.x;
  if (v >= 1204224) return;                 // 2*3*16*224*224/4
  const int hw4 = v % 12544;
  const int rest = v / 12544;
  const int t = rest & 15;
  const int bc = rest >> 4;
  const int c = bc % 3;
  const int b = bc / 3;
  const float4 rg = reinterpret_cast<const float4*>(rgbs)[v];
  float4 mk = reinterpret_cast<const float4*>(mask)[(b * 16 + t) * 12544 + hw4];
  if (flip) { mk.x = 1.f - mk.x; mk.y = 1.f - mk.y; mk.z = 1.f - mk.z; mk.w = 1.f - mk.w; }
  const float4 bgv = reinterpret_cast<const float4*>(bg)[c * 12544 + hw4];
  ushort4 o;
  o.x = f2bf(rg.x * mk.x + bgv.x * (1.f - mk.x));
  o.y = f2bf(rg.y * mk.y + bgv.y * (1.f - mk.y));
  o.z = f2bf(rg.z * mk.z + bgv.z * (1.f - mk.z));
  o.w = f2bf(rg.w * mk.w + bgv.w * (1.f - mk.w));
  reinterpret_cast<ushort4*>(out)[v] = o;
}

// fused maxpool + spatial sum (bf16 in): one block per (b,oc,t)
__global__ __launch_bounds__(256) void pool_sum_k(const ushort* __restrict__ in,
                                                  float* __restrict__ psums) {
  const int blk = blockIdx.x;
  const ushort* p = in + (size_t)blk * (HO * HO);
  float s = 0.f;
  for (int idx = threadIdx.x; idx < PO * PO; idx += 256) {
    const int ho = idx / PO, wo = idx % PO;
    ushort m = 0;
    for (int dh = 0; dh < 3; dh++) {
      const int ih = 2 * ho + dh;
      if (ih >= HO) break;
      for (int dw = 0; dw < 3; dw++) {
        const int iw = 2 * wo + dw;
        if (iw >= HO) break;
        const ushort v = p[ih * HO + iw];
        m = (v > m) ? v : m;
      }
    }
    s += bf2f(m);
  }
  __shared__ float red[256];
  red[threadIdx.x] = s;
  __syncthreads();
  for (int off = 128; off > 0; off >>= 1) {
    if (threadIdx.x < off) red[threadIdx.x] += red[threadIdx.x + off];
    __syncthreads();
  }
  if (threadIdx.x == 0) psums[blk] = red[0];
}

__global__ void logits_k(const float* __restrict__ psums, const float* __restrict__ Wl,
                         const float* __restrict__ bl, float* __restrict__ out) {
  const int idx = blockIdx.x * 256 + threadIdx.x;
  if (idx >= 800) return;
  const int b = idx / 400, l = idx % 400;
  float s = bl[l];
  for (int oc = 0; oc < 64; oc++) {
    float ps = 0.f;
    for (int t = 0; t < 8; t++) ps += psums[(b * 64 + oc) * 8 + t];
    s += (ps * (1.f / 25088.f)) * Wl[oc * 400 + l];
  }
  out[b * 400 + l] = s;
}

extern "C" void kernel_launch(void* const* d_in, const int* in_sizes, int n_in,
                              void* d_out, int out_size, void* d_ws, size_t ws_size,
                              hipStream_t stream) {
  const float* rgbs   = (const float*)d_in[0];
  const float* flows  = (const float*)d_in[1];
  const float* bg     = (const float*)d_in[2];
  const float* w_rgb  = (const float*)d_in[3];
  const float* w_flow = (const float*)d_in[4];
  const float* w_feat = (const float*)d_in[5];
  const float* W1     = (const float*)d_in[6];
  const float* b1     = (const float*)d_in[7];
  const float* W2     = (const float*)d_in[8];
  const float* b2     = (const float*)d_in[9];
  const float* W3     = (const float*)d_in[10];
  const float* b3     = (const float*)d_in[11];
  const float* Wl     = (const float*)d_in[12];
  const float* bl     = (const float*)d_in[13];
  float* out = (float*)d_out;

  float* ws = (float*)d_ws;
  float*  part    = ws;                             // 7,340,032 f
  ushort* convbuf = (ushort*)ws;                    // 12,845,056 ush (aliases part; disjoint in time)
  ushort* X       = (ushort*)(ws + 7500032);        // 6,422,528 ush
  ushort* masked  = (ushort*)(ws + 10711296);       // 4,816,896 ush
  float*  h1      = ws + 13200000;                  // 262,144
  float*  h2      = h1 + 262144;                    // 65,536
  float*  msmall  = h2 + 65536;                     // 256
  float*  psums0  = msmall + 256;                   // 1024
  float*  psums1  = psums0 + 1024;                  // 1024
  ushort* wrgb_b  = (ushort*)(psums1 + 1024);       // 100,352 ush each
  ushort* wflow_b = wrgb_b + 100352;
  ushort* wfeat_b = wflow_b + 100352;

  float* mask_full = out + 1600;

  const dim3 cgrid(112, 8, 2);
  const int WPG = (64 * 7 * 7 * 32 + 255) / 256;   // 392

  wprep<3><<<WPG, 256, 0, stream>>>(w_rgb, wrgb_b);
  wprep<2><<<WPG, 256, 0, stream>>>(w_flow, wflow_b);
  wprep<3><<<WPG, 256, 0, stream>>>(w_feat, wfeat_b);

  conv_mfma<3, float><<<cgrid, 256, 0, stream>>>(rgbs, wrgb_b, convbuf);
  maxpool_gather<<<(3211264 + 255) / 256, 256, 0, stream>>>(convbuf, X, 0);
  conv_mfma<2, float><<<cgrid, 256, 0, stream>>>(flows, wflow_b, convbuf);
  maxpool_gather<<<(3211264 + 255) / 256, 256, 0, stream>>>(convbuf, X, 12544);

  fcl1_mfma<<<dim3(8, 28), 512, 0, stream>>>(X, W1, part);
  h1_reduce<<<256, 256, 0, stream>>>(part, b1, h1);
  fcl2_k<<<256, 256, 0, stream>>>(h1, W2, b2, h2);
  fcl3_k<<<1, 256, 0, stream>>>(h2, W3, b3, msmall);
  upsample_k<<<(1605632 + 255) / 256, 256, 0, stream>>>(msmall, mask_full);

  masking_k<<<(1204224 + 255) / 256, 256, 0, stream>>>(rgbs, mask_full, bg, masked, 0);
  conv_mfma<3, ushort><<<cgrid, 256, 0, stream>>>(masked, wfeat_b, convbuf);
  pool_sum_k<<<1024, 256, 0, stream>>>(convbuf, psums0);

  masking_k<<<(1204224 + 255) / 256, 256, 0, stream>>>(rgbs, mask_full, bg, masked, 1);
  conv_mfma<3, ushort><<<cgrid, 256, 0, stream>>>(masked, wfeat_b, convbuf);
  pool_sum_k<<<1024, 256, 0, stream>>>(convbuf, psums1);

  logits_k<<<4, 256, 0, stream>>>(psums0, Wl, bl, out);
  logits_k<<<4, 256, 0, stream>>>(psums1, Wl, bl, out + 800);
}

// Round 7
// 670.254 us; speedup vs baseline: 1.1639x; 1.1639x over previous
//
#include <hip/hip_runtime.h>
#include <hip/hip_bf16.h>
#include <math.h>

#define IHW 224
#define DIN 16
#define DOUT 8
#define HO 112
#define PO 56

typedef __bf16 bf16x8 __attribute__((ext_vector_type(8)));
typedef float f32x4 __attribute__((ext_vector_type(4)));
typedef float f32x16 __attribute__((ext_vector_type(16)));
typedef ushort u16x8 __attribute__((ext_vector_type(8)));

__device__ __forceinline__ ushort f2bf(float f) {
  uint u = __float_as_uint(f);
  uint r = (u + 0x7FFFu + ((u >> 16) & 1u)) >> 16;
  return (ushort)r;
}
__device__ __forceinline__ float bf2f(ushort u) {
  return __uint_as_float(((uint)u) << 16);
}

// ---------------- f32 -> bf16 streaming convert (float4 -> ushort4) ----------------
__global__ void cvt_bf16(const float* __restrict__ in, ushort* __restrict__ out, int n4) {
  const int v = blockIdx.x * 256 + threadIdx.x;
  if (v >= n4) return;
  const float4 f = reinterpret_cast<const float4*>(in)[v];
  ushort4 o;
  o.x = f2bf(f.x); o.y = f2bf(f.y); o.z = f2bf(f.z); o.w = f2bf(f.w);
  reinterpret_cast<ushort4*>(out)[v] = o;
}

// ---------------- weight prep: f32 [64][C][7][7][7] -> bf16 [oc][kw][KPAD] ----------------
// k = kd*(C*7) + c*7 + kh  (zeros for k >= C*49)
template<int C>
__global__ __launch_bounds__(256) void wprep(const float* __restrict__ w, ushort* __restrict__ wB) {
  constexpr int C7 = C * 7, KREAL = C * 49, KPAD = (C == 3) ? 160 : 128;
  const int idx = blockIdx.x * 256 + threadIdx.x;
  if (idx >= 64 * 7 * KPAD) return;
  const int k = idx % KPAD;
  const int rest = idx / KPAD;
  const int kw = rest % 7;
  const int oc = rest / 7;
  float val = 0.f;
  if (k < KREAL) {
    const int kd = k / C7, rem = k % C7, c = rem / 7, kh = rem % 7;
    val = w[(((oc * C + c) * 7 + kd) * 7 + kh) * 7 + kw];
  }
  wB[idx] = f2bf(val);
}

// ---------------- conv3d 7x7x7 s2 SAME + ReLU via bf16 MFMA (wo-split halves) ----------------
// block = (ho*2+half, dd, b); computes out[b][0..63][dd][ho][half*56 .. half*56+55]  (bf16 out)
// LDS: sT[s_l=0..117][KPAD] bf16 XOR-swizzled (XOR stays within 128-aligned blocks -> in bounds)
template<int C>
__global__ __launch_bounds__(256, 4) void conv_mfma(
    const ushort* __restrict__ in, const ushort* __restrict__ wB,
    ushort* __restrict__ out)
{
  constexpr int C7 = C * 7, KREAL = C * 49;
  constexpr int KPAD = (C == 3) ? 160 : 128;
  constexpr int NKIT = KPAD / 32;
  constexpr int ROWB = KPAD * 2;
  constexpr int KG = KPAD / 4;
  constexpr int SROWS = 118;

  __shared__ char smem[SROWS * ROWB];
  __shared__ int offt[KPAD];

  const int hx = blockIdx.x;
  const int ho = hx >> 1, half = hx & 1;
  const int dd = blockIdx.y;
  const int b  = blockIdx.z;
  const int tid = threadIdx.x;
  const int lane = tid & 63;
  const int wv = tid >> 6;

  // ---- per-block k -> input-plane offset table ----
  if (tid < KPAD) {
    int off = -1;
    const int k = tid;
    if (k < KREAL) {
      const int kd = k / C7, rem = k % C7, c = rem / 7, kh = rem % 7;
      const int id = 2 * dd + kd - 2;
      const int ih = 2 * ho + kh - 2;
      if (id >= 0 && id < DIN && ih >= 0 && ih < IHW)
        off = (((b * C + c) * DIN + id) * IHW + ih) * IHW;
    }
    offt[tid] = off;
  }
  __syncthreads();

  // ---- stage: 236 threads, each one s-row x half the k-groups ----
  {
    const int s_l = tid & 127;
    const int grp = tid >> 7;
    if (s_l < SROWS) {
      const int iw = half * 112 + s_l - 2;
      const bool wok = (iw >= 0) && (iw < IHW);
      const int xr = ((s_l >> 1) & 7) << 4;
      for (int kg = grp * (KG / 2); kg < (grp + 1) * (KG / 2); kg++) {
        const int4 ot = *reinterpret_cast<const int4*>(&offt[kg * 4]);
        const int offs[4] = {ot.x, ot.y, ot.z, ot.w};
        ushort pk[4];
#pragma unroll
        for (int j = 0; j < 4; j++) {
          ushort v = 0;
          if (wok && offs[j] >= 0) v = in[(size_t)offs[j] + iw];
          pk[j] = v;
        }
        const int byte = (s_l * ROWB + kg * 8) ^ xr;
        *reinterpret_cast<ushort4*>(smem + byte) = make_ushort4(pk[0], pk[1], pk[2], pk[3]);
      }
    }
  }
  __syncthreads();

  // ---- MFMA: 4 waves = 2 M-halves x 2 N-halves; each wave 2 mt x 2 nt of 16x16 ----
  const int mhalf = wv >> 1, nhalf = wv & 1;
  const int row16 = lane & 15, ksub = lane >> 4;

  int s0[2];
#pragma unroll
  for (int mt = 0; mt < 2; mt++) {
    int wo_l = mhalf * 32 + mt * 16 + row16;    // 0..63, 56..63 dead
    if (wo_l > 55) wo_l = 55;                   // clamp, discarded in epilogue
    s0[mt] = 2 * wo_l;
  }
  const ushort* wq0 = wB + (size_t)(nhalf * 32 + row16) * (7 * KPAD) + ksub * 8;
  const ushort* wq1 = wq0 + (size_t)16 * (7 * KPAD);

  f32x4 acc[2][2] = {};

#pragma unroll
  for (int kw = 0; kw < 7; kw++) {
#pragma unroll
    for (int kit = 0; kit < NKIT; kit++) {
      const bf16x8 b0 = *reinterpret_cast<const bf16x8*>(wq0 + kw * KPAD + kit * 32);
      const bf16x8 b1 = *reinterpret_cast<const bf16x8*>(wq1 + kw * KPAD + kit * 32);
#pragma unroll
      for (int mt = 0; mt < 2; mt++) {
        const int s = s0[mt] + kw;
        const int byte = (s * ROWB + (kit * 4 + ksub) * 16) ^ (((s >> 1) & 7) << 4);
        const bf16x8 a = *reinterpret_cast<const bf16x8*>(smem + byte);
        acc[mt][0] = __builtin_amdgcn_mfma_f32_16x16x32_bf16(a, b0, acc[mt][0], 0, 0, 0);
        acc[mt][1] = __builtin_amdgcn_mfma_f32_16x16x32_bf16(a, b1, acc[mt][1], 0, 0, 0);
      }
    }
  }

  // ---- epilogue: transpose via LDS (bf16), coalesced ushort4 stores ----
  __syncthreads();
  ushort* eLDS = reinterpret_cast<ushort*>(smem);  // [64 oc][60]
#pragma unroll
  for (int mt = 0; mt < 2; mt++) {
    const int wo_b = mhalf * 32 + mt * 16 + ksub * 4;
    if (wo_b < 56) {
#pragma unroll
      for (int n = 0; n < 2; n++) {
        const int oc = nhalf * 32 + n * 16 + row16;
        ushort4 r4;
        r4.x = f2bf(fmaxf(acc[mt][n][0], 0.f));
        r4.y = f2bf(fmaxf(acc[mt][n][1], 0.f));
        r4.z = f2bf(fmaxf(acc[mt][n][2], 0.f));
        r4.w = f2bf(fmaxf(acc[mt][n][3], 0.f));
        *reinterpret_cast<ushort4*>(eLDS + oc * 60 + wo_b) = r4;
      }
    }
  }
  __syncthreads();
  ushort* gout = out + ((size_t)(b * 64) * DOUT + dd) * (HO * HO) + ho * HO + half * 56;
#pragma unroll
  for (int i = 0; i < 4; i++) {
    const int idx = i * 256 + tid;          // 64 oc x 14 w4 = 896
    if (idx < 896) {
      const int oc = idx / 14;
      const int w4 = idx - oc * 14;
      *reinterpret_cast<ushort4*>(gout + (size_t)oc * DOUT * (HO * HO) + w4 * 4) =
          *reinterpret_cast<const ushort4*>(eLDS + oc * 60 + w4 * 4);
    }
  }
}

// ---------------- fused maxpool 3x3 s2 SAME + gather into GEMM X layout (bf16) ----------------
__global__ void maxpool_gather(const ushort* __restrict__ in, ushort* __restrict__ X, int fbase) {
  const int idx = blockIdx.x * 256 + threadIdx.x;
  if (idx >= 2 * 64 * 8 * PO * PO) return;
  const int wo = idx % PO;
  const int ho = (idx / PO) % PO;
  const int rest = idx / (PO * PO);          // (b*64+c)*8+t
  const ushort* p = in + (size_t)rest * (HO * HO);
  ushort m = 0;
  for (int dh = 0; dh < 3; dh++) {
    const int ih = 2 * ho + dh;
    if (ih >= HO) break;
    for (int dw = 0; dw < 3; dw++) {
      const int iw = 2 * wo + dw;
      if (iw >= HO) break;
      const ushort v = p[ih * HO + iw];
      m = (v > m) ? v : m;
    }
  }
  const int t = rest % 8;
  const int c = (rest / 8) % 64;
  const int b = rest / 512;
  const int r = ((b * 8 + t) * 4 + ho / 14) * 4 + (wo / 14);
  const int f = fbase + c * 196 + (ho % 14) * 14 + (wo % 14);
  X[(size_t)r * 25088 + f] = m;
}

// ---------------- FCL1: X[256][25088] bf16 @ W1bf[25088][1024] bf16 -> part bf16 ----------------
// grid (bn=8, kc=28); BM=256 BN=128 BK=64; 512 thr = 8 waves (4M x 2N), 32x32x16
__global__ __launch_bounds__(512) void fcl1_mfma(
    const ushort* __restrict__ X, const ushort* __restrict__ W1bf, ushort* __restrict__ part)
{
  const int bn = blockIdx.x;
  const int kc = blockIdx.y;
  const int tid = threadIdx.x;
  const int lane = tid & 63;
  const int wv = tid >> 6;
  const int wm = wv >> 1, wn = wv & 1;
  const int l31 = lane & 31, kh = lane >> 5;

  __shared__ char xs[256 * 128];   // [r][64k] bf16, swz ((r&7)<<4)
  __shared__ char wsm[128 * 128];  // [n][64k] bf16, swz ((n&7)<<4)

  f32x16 acc[2][2] = {};

  const int kchunk0 = kc * 896;

  for (int kt = 0; kt < 14; kt++) {
    const int k0 = kchunk0 + kt * 64;
    __syncthreads();
    // stage X: 4 x 16B per thread (256 rows x 8 chunks)
#pragma unroll
    for (int i = 0; i < 4; i++) {
      const int chunk = tid + 512 * i;
      const int r = chunk >> 3, c8 = chunk & 7;
      const int4 v = *reinterpret_cast<const int4*>(X + (size_t)r * 25088 + k0 + c8 * 8);
      int byte = r * 128 + c8 * 16;
      byte ^= ((r & 7) << 4);
      *reinterpret_cast<int4*>(xs + byte) = v;
    }
    // stage W (bf16): 2 k-rows x 8 n per thread -> 8 packed uint scattered writes
    {
      const int nq = tid & 15, kp = tid >> 4;   // kp 0..31
      const int kk = kp * 2;
      const u16x8 a = *reinterpret_cast<const u16x8*>(W1bf + (size_t)(k0 + kk) * 1024 + bn * 128 + nq * 8);
      const u16x8 bq = *reinterpret_cast<const u16x8*>(W1bf + (size_t)(k0 + kk + 1) * 1024 + bn * 128 + nq * 8);
#pragma unroll
      for (int j = 0; j < 8; j++) {
        const int n = nq * 8 + j;
        const uint pack = (uint)a[j] | ((uint)bq[j] << 16);
        const int byte = (n * 128 + kk * 2) ^ ((n & 7) << 4);
        *reinterpret_cast<uint*>(wsm + byte) = pack;
      }
    }
    __syncthreads();
#pragma unroll
    for (int ks = 0; ks < 4; ks++) {
      bf16x8 af[2], bfr[2];
#pragma unroll
      for (int m = 0; m < 2; m++) {
        const int r = wm * 64 + m * 32 + l31;
        const int byte = (r * 128 + ks * 32 + kh * 16) ^ ((r & 7) << 4);
        af[m] = *reinterpret_cast<const bf16x8*>(xs + byte);
      }
#pragma unroll
      for (int n = 0; n < 2; n++) {
        const int c = wn * 64 + n * 32 + l31;
        const int byte = (c * 128 + ks * 32 + kh * 16) ^ ((c & 7) << 4);
        bfr[n] = *reinterpret_cast<const bf16x8*>(wsm + byte);
      }
#pragma unroll
      for (int m = 0; m < 2; m++)
#pragma unroll
        for (int n = 0; n < 2; n++)
          acc[m][n] = __builtin_amdgcn_mfma_f32_32x32x16_bf16(af[m], bfr[n], acc[m][n], 0, 0, 0);
    }
  }

  ushort* pout = part + (size_t)kc * (256 * 1024);
#pragma unroll
  for (int m = 0; m < 2; m++)
#pragma unroll
    for (int n = 0; n < 2; n++)
#pragma unroll
      for (int rg = 0; rg < 16; rg++) {
        const int row = wm * 64 + m * 32 + (rg & 3) + 8 * (rg >> 2) + 4 * kh;
        const int col = bn * 128 + wn * 64 + n * 32 + l31;
        pout[(size_t)row * 1024 + col] = f2bf(acc[m][n][rg]);
      }
}

// h1 = relu(b1 + sum_kc part_bf16)
__global__ void h1_reduce(const ushort* __restrict__ part, const float* __restrict__ b1,
                          float* __restrict__ h1) {
  const int v = blockIdx.x * 256 + threadIdx.x;  // < 32768 = 256r x 128 n8
  if (v >= 32768) return;
  const int r = v >> 7, n8 = v & 127;
  float s[8];
#pragma unroll
  for (int j = 0; j < 8; j++) s[j] = b1[n8 * 8 + j];
  for (int kc = 0; kc < 28; kc++) {
    const u16x8 p = *reinterpret_cast<const u16x8*>(part + (size_t)kc * 262144 + r * 1024 + n8 * 8);
#pragma unroll
    for (int j = 0; j < 8; j++) s[j] += bf2f(p[j]);
  }
#pragma unroll
  for (int j = 0; j < 8; j++) h1[r * 1024 + n8 * 8 + j] = fmaxf(s[j], 0.f);
}

__global__ __launch_bounds__(256) void fcl2_k(const float* __restrict__ h1,
                                              const float* __restrict__ W2,
                                              const float* __restrict__ b2,
                                              float* __restrict__ h2) {
  const int r = blockIdx.x;
  const int n = threadIdx.x;
  __shared__ float xr[1024];
  for (int i = threadIdx.x; i < 1024; i += 256) xr[i] = h1[r * 1024 + i];
  __syncthreads();
  float s = b2[n];
  for (int k = 0; k < 1024; k++) s += xr[k] * W2[k * 256 + n];
  h2[r * 256 + n] = fmaxf(s, 0.f);
}

__global__ void fcl3_k(const float* __restrict__ h2, const float* __restrict__ W3,
                       const float* __restrict__ b3, float* __restrict__ ms) {
  __shared__ float w[256];
  w[threadIdx.x] = W3[threadIdx.x];
  __syncthreads();
  const int r = threadIdx.x;
  float s = b3[0];
  for (int k = 0; k < 256; k++) s += h2[r * 256 + k] * w[k];
  ms[r] = 1.f / (1.f + expf(-s));
}

__global__ void upsample_k(const float* __restrict__ ms, float* __restrict__ mask) {
  const int idx = blockIdx.x * 256 + threadIdx.x;
  if (idx >= 2 * 16 * IHW * IHW) return;
  const int w = idx % IHW;
  const int h = (idx / IHW) % IHW;
  const int t = (idx / (IHW * IHW)) % 16;
  const int b = idx / (16 * IHW * IHW);

  const float tf = t * 0.5f - 0.25f;
  const float hf = (h + 0.5f) * (1.f / 56.f) - 0.5f;
  const float wf = (w + 0.5f) * (1.f / 56.f) - 0.5f;

  int t0 = (int)floorf(tf); const float ft = tf - t0;
  int h0 = (int)floorf(hf); const float fh = hf - h0;
  int w0 = (int)floorf(wf); const float fw = wf - w0;
  const int t1 = min(t0 + 1, 7); t0 = max(t0, 0);
  const int h1 = min(h0 + 1, 3); h0 = max(h0, 0);
  const int w1 = min(w0 + 1, 3); w0 = max(w0, 0);

  const float* p = ms + b * 128;
  auto at = [&](int tt, int hh, int ww) { return p[(tt * 4 + hh) * 4 + ww]; };
  const float c00 = at(t0, h0, w0) * (1.f - fw) + at(t0, h0, w1) * fw;
  const float c01 = at(t0, h1, w0) * (1.f - fw) + at(t0, h1, w1) * fw;
  const float c10 = at(t1, h0, w0) * (1.f - fw) + at(t1, h0, w1) * fw;
  const float c11 = at(t1, h1, w0) * (1.f - fw) + at(t1, h1, w1) * fw;
  const float c0 = c00 * (1.f - fh) + c01 * fh;
  const float c1 = c10 * (1.f - fh) + c11 * fh;
  mask[idx] = c0 * (1.f - ft) + c1 * ft;
}

// masked = rgbs*m + bg*(1-m) -> bf16; flip -> m := 1-m
__global__ void masking_k(const float* __restrict__ rgbs, const float* __restrict__ mask,
                          const float* __restrict__ bg, ushort* __restrict__ out, int flip) {
  const int v = blockIdx.x * 256 + threadIdx.x;
  if (v >= 1204224) return;                 // 2*3*16*224*224/4
  const int hw4 = v % 12544;
  const int rest = v / 12544;
  const int t = rest & 15;
  const int bc = rest >> 4;
  const int c = bc % 3;
  const int b = bc / 3;
  const float4 rg = reinterpret_cast<const float4*>(rgbs)[v];
  float4 mk = reinterpret_cast<const float4*>(mask)[(b * 16 + t) * 12544 + hw4];
  if (flip) { mk.x = 1.f - mk.x; mk.y = 1.f - mk.y; mk.z = 1.f - mk.z; mk.w = 1.f - mk.w; }
  const float4 bgv = reinterpret_cast<const float4*>(bg)[c * 12544 + hw4];
  ushort4 o;
  o.x = f2bf(rg.x * mk.x + bgv.x * (1.f - mk.x));
  o.y = f2bf(rg.y * mk.y + bgv.y * (1.f - mk.y));
  o.z = f2bf(rg.z * mk.z + bgv.z * (1.f - mk.z));
  o.w = f2bf(rg.w * mk.w + bgv.w * (1.f - mk.w));
  reinterpret_cast<ushort4*>(out)[v] = o;
}

// fused maxpool + spatial sum (bf16 in): one block per (b,oc,t)
__global__ __launch_bounds__(256) void pool_sum_k(const ushort* __restrict__ in,
                                                  float* __restrict__ psums) {
  const int blk = blockIdx.x;
  const ushort* p = in + (size_t)blk * (HO * HO);
  float s = 0.f;
  for (int idx = threadIdx.x; idx < PO * PO; idx += 256) {
    const int ho = idx / PO, wo = idx % PO;
    ushort m = 0;
    for (int dh = 0; dh < 3; dh++) {
      const int ih = 2 * ho + dh;
      if (ih >= HO) break;
      for (int dw = 0; dw < 3; dw++) {
        const int iw = 2 * wo + dw;
        if (iw >= HO) break;
        const ushort v = p[ih * HO + iw];
        m = (v > m) ? v : m;
      }
    }
    s += bf2f(m);
  }
  __shared__ float red[256];
  red[threadIdx.x] = s;
  __syncthreads();
  for (int off = 128; off > 0; off >>= 1) {
    if (threadIdx.x < off) red[threadIdx.x] += red[threadIdx.x + off];
    __syncthreads();
  }
  if (threadIdx.x == 0) psums[blk] = red[0];
}

__global__ void logits_k(const float* __restrict__ psums, const float* __restrict__ Wl,
                         const float* __restrict__ bl, float* __restrict__ out) {
  const int idx = blockIdx.x * 256 + threadIdx.x;
  if (idx >= 800) return;
  const int b = idx / 400, l = idx % 400;
  float s = bl[l];
  for (int oc = 0; oc < 64; oc++) {
    float ps = 0.f;
    for (int t = 0; t < 8; t++) ps += psums[(b * 64 + oc) * 8 + t];
    s += (ps * (1.f / 25088.f)) * Wl[oc * 400 + l];
  }
  out[b * 400 + l] = s;
}

extern "C" void kernel_launch(void* const* d_in, const int* in_sizes, int n_in,
                              void* d_out, int out_size, void* d_ws, size_t ws_size,
                              hipStream_t stream) {
  const float* rgbs   = (const float*)d_in[0];
  const float* flows  = (const float*)d_in[1];
  const float* bg     = (const float*)d_in[2];
  const float* w_rgb  = (const float*)d_in[3];
  const float* w_flow = (const float*)d_in[4];
  const float* w_feat = (const float*)d_in[5];
  const float* W1     = (const float*)d_in[6];
  const float* b1     = (const float*)d_in[7];
  const float* W2     = (const float*)d_in[8];
  const float* b2     = (const float*)d_in[9];
  const float* W3     = (const float*)d_in[10];
  const float* b3     = (const float*)d_in[11];
  const float* Wl     = (const float*)d_in[12];
  const float* bl     = (const float*)d_in[13];
  float* out = (float*)d_out;

  float* ws = (float*)d_ws;
  // region A [0, 6,422,528)f : convbuf (bf16 conv outputs) / part (bf16 fcl1 partials) — time-disjoint
  ushort* convbuf = (ushort*)ws;                    // 12,845,056 ush
  ushort* part    = (ushort*)ws;                    // 7,340,032 ush
  // X [6,500,000, 9,711,264)f
  ushort* X       = (ushort*)(ws + 6500000);        // 6,422,528 ush
  // W1bf region [9,711,264, 22,556,320)f ; rgbsB/flowsB (die before W1bf cvt) and
  // masked (lives after fcl1) alias its start
  ushort* W1bf    = (ushort*)(ws + 9711264);        // 25,690,112 ush
  ushort* rgbsB   = (ushort*)(ws + 9711264);        // 4,816,896 ush (2,408,448 f)
  ushort* flowsB  = (ushort*)(ws + 12119712);       // 3,211,264 ush (1,605,632 f)
  ushort* masked  = (ushort*)(ws + 9711264);        // 4,816,896 ush
  // tail
  float*  h1      = ws + 22556320;                  // 262,144
  float*  h2      = h1 + 262144;                    // 65,536
  float*  msmall  = h2 + 65536;                     // 256
  float*  psums0  = msmall + 256;                   // 1024
  float*  psums1  = psums0 + 1024;                  // 1024
  ushort* wrgb_b  = (ushort*)(psums1 + 1024);       // 71,680 ush
  ushort* wflow_b = wrgb_b + 71680;                 // 57,344 ush
  ushort* wfeat_b = wflow_b + 57344;                // 71,680 ush

  float* mask_full = out + 1600;

  const dim3 cgrid(224, 8, 2);

  // --- input/weight bf16 prep ---
  cvt_bf16<<<(1204224 + 255) / 256, 256, 0, stream>>>(rgbs, rgbsB, 1204224);   // 4,816,896/4
  cvt_bf16<<<(802816 + 255) / 256, 256, 0, stream>>>(flows, flowsB, 802816);   // 3,211,264/4
  wprep<3><<<(64 * 7 * 160 + 255) / 256, 256, 0, stream>>>(w_rgb, wrgb_b);
  wprep<2><<<(64 * 7 * 128 + 255) / 256, 256, 0, stream>>>(w_flow, wflow_b);
  wprep<3><<<(64 * 7 * 160 + 255) / 256, 256, 0, stream>>>(w_feat, wfeat_b);

  // --- mask branch stems ---
  conv_mfma<3><<<cgrid, 256, 0, stream>>>(rgbsB, wrgb_b, convbuf);
  maxpool_gather<<<(3211264 + 255) / 256, 256, 0, stream>>>(convbuf, X, 0);
  conv_mfma<2><<<cgrid, 256, 0, stream>>>(flowsB, wflow_b, convbuf);
  maxpool_gather<<<(3211264 + 255) / 256, 256, 0, stream>>>(convbuf, X, 12544);

  // rgbsB/flowsB now dead -> W1 bf16 convert into the same region
  cvt_bf16<<<(6422528 + 255) / 256, 256, 0, stream>>>(W1, W1bf, 6422528);

  fcl1_mfma<<<dim3(8, 28), 512, 0, stream>>>(X, W1bf, part);
  h1_reduce<<<128, 256, 0, stream>>>(part, b1, h1);
  fcl2_k<<<256, 256, 0, stream>>>(h1, W2, b2, h2);
  fcl3_k<<<1, 256, 0, stream>>>(h2, W3, b3, msmall);
  upsample_k<<<(1605632 + 255) / 256, 256, 0, stream>>>(msmall, mask_full);

  // --- feature head 0 --- (masked aliases W1bf region; W1bf dead after fcl1)
  masking_k<<<(1204224 + 255) / 256, 256, 0, stream>>>(rgbs, mask_full, bg, masked, 0);
  conv_mfma<3><<<cgrid, 256, 0, stream>>>(masked, wfeat_b, convbuf);
  pool_sum_k<<<1024, 256, 0, stream>>>(convbuf, psums0);

  // --- feature head 1 ---
  masking_k<<<(1204224 + 255) / 256, 256, 0, stream>>>(rgbs, mask_full, bg, masked, 1);
  conv_mfma<3><<<cgrid, 256, 0, stream>>>(masked, wfeat_b, convbuf);
  pool_sum_k<<<1024, 256, 0, stream>>>(convbuf, psums1);

  logits_k<<<4, 256, 0, stream>>>(psums0, Wl, bl, out);
  logits_k<<<4, 256, 0, stream>>>(psums1, Wl, bl, out + 800);
}

// Round 8
// 580.723 us; speedup vs baseline: 1.3433x; 1.1542x over previous
//
#include <hip/hip_runtime.h>
#include <hip/hip_bf16.h>
#include <math.h>

#define IHW 224
#define DIN 16
#define DOUT 8
#define HO 112
#define PO 56

typedef __bf16 bf16x8 __attribute__((ext_vector_type(8)));
typedef float f32x4 __attribute__((ext_vector_type(4)));
typedef float f32x16 __attribute__((ext_vector_type(16)));
typedef ushort u16x8 __attribute__((ext_vector_type(8)));

__device__ __forceinline__ ushort f2bf(float f) {
  uint u = __float_as_uint(f);
  uint r = (u + 0x7FFFu + ((u >> 16) & 1u)) >> 16;
  return (ushort)r;
}
__device__ __forceinline__ float bf2f(ushort u) {
  return __uint_as_float(((uint)u) << 16);
}

// ---------------- f32 -> bf16 streaming convert (float4 -> ushort4) ----------------
__global__ void cvt_bf16(const float* __restrict__ in, ushort* __restrict__ out, int n4) {
  const int v = blockIdx.x * 256 + threadIdx.x;
  if (v >= n4) return;
  const float4 f = reinterpret_cast<const float4*>(in)[v];
  ushort4 o;
  o.x = f2bf(f.x); o.y = f2bf(f.y); o.z = f2bf(f.z); o.w = f2bf(f.w);
  reinterpret_cast<ushort4*>(out)[v] = o;
}

// ---------------- weight prep: f32 [64][C][7][7][7] -> bf16 [oc][kw][KPAD] ----------------
// k = kd*(C*7) + c*7 + kh  (zeros for k >= C*49)
template<int C>
__global__ __launch_bounds__(256) void wprep(const float* __restrict__ w, ushort* __restrict__ wB) {
  constexpr int C7 = C * 7, KREAL = C * 49, KPAD = (C == 3) ? 160 : 128;
  const int idx = blockIdx.x * 256 + threadIdx.x;
  if (idx >= 64 * 7 * KPAD) return;
  const int k = idx % KPAD;
  const int rest = idx / KPAD;
  const int kw = rest % 7;
  const int oc = rest / 7;
  float val = 0.f;
  if (k < KREAL) {
    const int kd = k / C7, rem = k % C7, c = rem / 7, kh = rem % 7;
    val = w[(((oc * C + c) * 7 + kd) * 7 + kh) * 7 + kw];
  }
  wB[idx] = f2bf(val);
}

// ---------------- conv3d 7x7x7 s2 SAME + ReLU via bf16 MFMA (wo-split halves) ----------------
// block = (ho*2+half, dd, bb); out[bb][0..63][dd][ho][half*56..+55] (bf16)
// bb spans batch-and-head merged (mask stems: z=2; feature heads: z=4)
// staging: phase-split (issue-all-loads -> write) batches of 4 units for MLP
template<int C>
__global__ __launch_bounds__(256, 4) void conv_mfma(
    const ushort* __restrict__ in, const ushort* __restrict__ wB,
    ushort* __restrict__ out)
{
  constexpr int C7 = C * 7, KREAL = C * 49;
  constexpr int KPAD = (C == 3) ? 160 : 128;
  constexpr int NKIT = KPAD / 32;
  constexpr int ROWB = KPAD * 2;
  constexpr int KG = KPAD / 4;
  constexpr int SROWS = 118;
  constexpr int NU = (KG * 128) / 256;     // 20 (C=3) / 16 (C=2), exact
  constexpr int NBATCH = NU / 4;

  __shared__ char smem[SROWS * ROWB];
  __shared__ int offt[KPAD];

  const int hx = blockIdx.x;
  const int ho = hx >> 1, half = hx & 1;
  const int dd = blockIdx.y;
  const int bb = blockIdx.z;
  const int tid = threadIdx.x;
  const int lane = tid & 63;
  const int wv = tid >> 6;

  // ---- per-block k -> input-plane offset table ----
  if (tid < KPAD) {
    int off = -1;
    const int k = tid;
    if (k < KREAL) {
      const int kd = k / C7, rem = k % C7, c = rem / 7, kh = rem % 7;
      const int id = 2 * dd + kd - 2;
      const int ih = 2 * ho + kh - 2;
      if (id >= 0 && id < DIN && ih >= 0 && ih < IHW)
        off = (((bb * C + c) * DIN + id) * IHW + ih) * IHW;
    }
    offt[tid] = off;
  }
  __syncthreads();

  // ---- stage: transposed sT[s][k] bf16 XOR-swizzled; batched issue-then-write ----
  for (int b4 = 0; b4 < NBATCH; b4++) {
    ushort pk[4][4];
    int sb[4];
#pragma unroll
    for (int i = 0; i < 4; i++) {
      const int u   = (b4 * 4 + i) * 256 + tid;
      const int kg  = u >> 7;              // < KG by construction
      const int s_l = u & 127;
      const int iw  = half * 112 + s_l - 2;
      const bool sok = (s_l < SROWS);
      const bool wok = sok && (iw >= 0) && (iw < IHW);
      const int iwc = min(max(iw, 0), IHW - 1);
      const int4 ot = *reinterpret_cast<const int4*>(&offt[kg * 4]);
      // unconditional clamped loads (keeps them batched), select after
      const ushort v0 = in[(size_t)max(ot.x, 0) + iwc];
      const ushort v1 = in[(size_t)max(ot.y, 0) + iwc];
      const ushort v2 = in[(size_t)max(ot.z, 0) + iwc];
      const ushort v3 = in[(size_t)max(ot.w, 0) + iwc];
      pk[i][0] = (wok && ot.x >= 0) ? v0 : (ushort)0;
      pk[i][1] = (wok && ot.y >= 0) ? v1 : (ushort)0;
      pk[i][2] = (wok && ot.z >= 0) ? v2 : (ushort)0;
      pk[i][3] = (wok && ot.w >= 0) ? v3 : (ushort)0;
      sb[i] = sok ? ((s_l * ROWB + kg * 8) ^ (((s_l >> 1) & 7) << 4)) : -1;
    }
#pragma unroll
    for (int i = 0; i < 4; i++) {
      if (sb[i] >= 0)
        *reinterpret_cast<ushort4*>(smem + sb[i]) =
            make_ushort4(pk[i][0], pk[i][1], pk[i][2], pk[i][3]);
    }
  }
  __syncthreads();

  // ---- MFMA: 4 waves = 2 M-halves x 2 N-halves; each wave 2 mt x 2 nt of 16x16 ----
  const int mhalf = wv >> 1, nhalf = wv & 1;
  const int row16 = lane & 15, ksub = lane >> 4;

  int s0[2];
#pragma unroll
  for (int mt = 0; mt < 2; mt++) {
    int wo_l = mhalf * 32 + mt * 16 + row16;    // 0..63; 56..63 dead
    if (wo_l > 55) wo_l = 55;                   // clamp, discarded in epilogue
    s0[mt] = 2 * wo_l;
  }
  const ushort* wq0 = wB + (size_t)(nhalf * 32 + row16) * (7 * KPAD) + ksub * 8;
  const ushort* wq1 = wq0 + (size_t)16 * (7 * KPAD);

  f32x4 acc[2][2] = {};

#pragma unroll
  for (int kw = 0; kw < 7; kw++) {
#pragma unroll
    for (int kit = 0; kit < NKIT; kit++) {
      const bf16x8 b0 = *reinterpret_cast<const bf16x8*>(wq0 + kw * KPAD + kit * 32);
      const bf16x8 b1 = *reinterpret_cast<const bf16x8*>(wq1 + kw * KPAD + kit * 32);
#pragma unroll
      for (int mt = 0; mt < 2; mt++) {
        const int s = s0[mt] + kw;
        const int byte = (s * ROWB + (kit * 4 + ksub) * 16) ^ (((s >> 1) & 7) << 4);
        const bf16x8 a = *reinterpret_cast<const bf16x8*>(smem + byte);
        acc[mt][0] = __builtin_amdgcn_mfma_f32_16x16x32_bf16(a, b0, acc[mt][0], 0, 0, 0);
        acc[mt][1] = __builtin_amdgcn_mfma_f32_16x16x32_bf16(a, b1, acc[mt][1], 0, 0, 0);
      }
    }
  }

  // ---- epilogue: transpose via LDS (bf16), coalesced ushort4 stores ----
  __syncthreads();
  ushort* eLDS = reinterpret_cast<ushort*>(smem);  // [64 oc][60]
#pragma unroll
  for (int mt = 0; mt < 2; mt++) {
    const int wo_b = mhalf * 32 + mt * 16 + ksub * 4;
    if (wo_b < 56) {
#pragma unroll
      for (int n = 0; n < 2; n++) {
        const int oc = nhalf * 32 + n * 16 + row16;
        ushort4 r4;
        r4.x = f2bf(fmaxf(acc[mt][n][0], 0.f));
        r4.y = f2bf(fmaxf(acc[mt][n][1], 0.f));
        r4.z = f2bf(fmaxf(acc[mt][n][2], 0.f));
        r4.w = f2bf(fmaxf(acc[mt][n][3], 0.f));
        *reinterpret_cast<ushort4*>(eLDS + oc * 60 + wo_b) = r4;
      }
    }
  }
  __syncthreads();
  ushort* gout = out + ((size_t)(bb * 64) * DOUT + dd) * (HO * HO) + ho * HO + half * 56;
#pragma unroll
  for (int i = 0; i < 4; i++) {
    const int idx = i * 256 + tid;          // 64 oc x 14 w4 = 896
    if (idx < 896) {
      const int oc = idx / 14;
      const int w4 = idx - oc * 14;
      *reinterpret_cast<ushort4*>(gout + (size_t)oc * DOUT * (HO * HO) + w4 * 4) =
          *reinterpret_cast<const ushort4*>(eLDS + oc * 60 + w4 * 4);
    }
  }
}

// ---------------- fused maxpool 3x3 s2 SAME + gather into GEMM X layout (bf16) ----------------
__global__ void maxpool_gather(const ushort* __restrict__ in, ushort* __restrict__ X, int fbase) {
  const int idx = blockIdx.x * 256 + threadIdx.x;
  if (idx >= 2 * 64 * 8 * PO * PO) return;
  const int wo = idx % PO;
  const int ho = (idx / PO) % PO;
  const int rest = idx / (PO * PO);          // (b*64+c)*8+t
  const ushort* p = in + (size_t)rest * (HO * HO);
  ushort m = 0;
  for (int dh = 0; dh < 3; dh++) {
    const int ih = 2 * ho + dh;
    if (ih >= HO) break;
    for (int dw = 0; dw < 3; dw++) {
      const int iw = 2 * wo + dw;
      if (iw >= HO) break;
      const ushort v = p[ih * HO + iw];
      m = (v > m) ? v : m;
    }
  }
  const int t = rest % 8;
  const int c = (rest / 8) % 64;
  const int b = rest / 512;
  const int r = ((b * 8 + t) * 4 + ho / 14) * 4 + (wo / 14);
  const int f = fbase + c * 196 + (ho % 14) * 14 + (wo % 14);
  X[(size_t)r * 25088 + f] = m;
}

// ---------------- FCL1: X[256][25088] bf16 @ W1[25088][1024] f32(cvt in-kernel) -> part bf16 ----------------
// grid (bn=8, kc=28); BM=256 BN=128 BK=64; 512 thr = 8 waves (4M x 2N), 32x32x16
__global__ __launch_bounds__(512) void fcl1_mfma(
    const ushort* __restrict__ X, const float* __restrict__ W1, ushort* __restrict__ part)
{
  const int bn = blockIdx.x;
  const int kc = blockIdx.y;
  const int tid = threadIdx.x;
  const int lane = tid & 63;
  const int wv = tid >> 6;
  const int wm = wv >> 1, wn = wv & 1;
  const int l31 = lane & 31, kh = lane >> 5;

  __shared__ char xs[256 * 128];   // [r][64k] bf16, swz ((r&7)<<4)
  __shared__ char wsm[128 * 128];  // [n][64k] bf16, swz ((n&7)<<4)

  f32x16 acc[2][2] = {};

  const int kchunk0 = kc * 896;

  for (int kt = 0; kt < 14; kt++) {
    const int k0 = kchunk0 + kt * 64;
    __syncthreads();
    // stage X: 4 x 16B per thread (256 rows x 8 chunks)
#pragma unroll
    for (int i = 0; i < 4; i++) {
      const int chunk = tid + 512 * i;
      const int r = chunk >> 3, c8 = chunk & 7;
      const int4 v = *reinterpret_cast<const int4*>(X + (size_t)r * 25088 + k0 + c8 * 8);
      int byte = r * 128 + c8 * 16;
      byte ^= ((r & 7) << 4);
      *reinterpret_cast<int4*>(xs + byte) = v;
    }
    // stage W: transpose + f32->bf16 (R4-validated)
    {
      const int nq = tid & 31, kp0 = tid >> 5;
#pragma unroll
      for (int h = 0; h < 2; h++) {
        const int kk = (kp0 + h * 16) * 2;
        const float4 a  = *reinterpret_cast<const float4*>(W1 + (size_t)(k0 + kk) * 1024 + bn * 128 + nq * 4);
        const float4 bq = *reinterpret_cast<const float4*>(W1 + (size_t)(k0 + kk + 1) * 1024 + bn * 128 + nq * 4);
        const float av[4] = {a.x, a.y, a.z, a.w};
        const float bv[4] = {bq.x, bq.y, bq.z, bq.w};
#pragma unroll
        for (int j = 0; j < 4; j++) {
          const int n = nq * 4 + j;
          const uint pack = (uint)f2bf(av[j]) | ((uint)f2bf(bv[j]) << 16);
          const int byte = (n * 128 + kk * 2) ^ ((n & 7) << 4);
          *reinterpret_cast<uint*>(wsm + byte) = pack;
        }
      }
    }
    __syncthreads();
#pragma unroll
    for (int ks = 0; ks < 4; ks++) {
      bf16x8 af[2], bfr[2];
#pragma unroll
      for (int m = 0; m < 2; m++) {
        const int r = wm * 64 + m * 32 + l31;
        const int byte = (r * 128 + ks * 32 + kh * 16) ^ ((r & 7) << 4);
        af[m] = *reinterpret_cast<const bf16x8*>(xs + byte);
      }
#pragma unroll
      for (int n = 0; n < 2; n++) {
        const int c = wn * 64 + n * 32 + l31;
        const int byte = (c * 128 + ks * 32 + kh * 16) ^ ((c & 7) << 4);
        bfr[n] = *reinterpret_cast<const bf16x8*>(wsm + byte);
      }
#pragma unroll
      for (int m = 0; m < 2; m++)
#pragma unroll
        for (int n = 0; n < 2; n++)
          acc[m][n] = __builtin_amdgcn_mfma_f32_32x32x16_bf16(af[m], bfr[n], acc[m][n], 0, 0, 0);
    }
  }

  ushort* pout = part + (size_t)kc * (256 * 1024);
#pragma unroll
  for (int m = 0; m < 2; m++)
#pragma unroll
    for (int n = 0; n < 2; n++)
#pragma unroll
      for (int rg = 0; rg < 16; rg++) {
        const int row = wm * 64 + m * 32 + (rg & 3) + 8 * (rg >> 2) + 4 * kh;
        const int col = bn * 128 + wn * 64 + n * 32 + l31;
        pout[(size_t)row * 1024 + col] = f2bf(acc[m][n][rg]);
      }
}

// h1 = relu(b1 + sum_kc part_bf16)
__global__ void h1_reduce(const ushort* __restrict__ part, const float* __restrict__ b1,
                          float* __restrict__ h1) {
  const int v = blockIdx.x * 256 + threadIdx.x;  // < 32768 = 256r x 128 n8
  if (v >= 32768) return;
  const int r = v >> 7, n8 = v & 127;
  float s[8];
#pragma unroll
  for (int j = 0; j < 8; j++) s[j] = b1[n8 * 8 + j];
  for (int kc = 0; kc < 28; kc++) {
    const u16x8 p = *reinterpret_cast<const u16x8*>(part + (size_t)kc * 262144 + r * 1024 + n8 * 8);
#pragma unroll
    for (int j = 0; j < 8; j++) s[j] += bf2f(p[j]);
  }
#pragma unroll
  for (int j = 0; j < 8; j++) h1[r * 1024 + n8 * 8 + j] = fmaxf(s[j], 0.f);
}

// h2 = relu(h1 @ W2 + b2): 4 rows per block (cuts W2 re-reads 4x)
__global__ __launch_bounds__(256) void fcl2_k(const float* __restrict__ h1,
                                              const float* __restrict__ W2,
                                              const float* __restrict__ b2,
                                              float* __restrict__ h2) {
  const int r0 = blockIdx.x * 4;
  const int n = threadIdx.x;
  __shared__ float xr[4][1024];
  for (int i = threadIdx.x; i < 4096; i += 256) xr[i >> 10][i & 1023] = h1[r0 * 1024 + i];
  __syncthreads();
  float acc[4] = {b2[n], b2[n], b2[n], b2[n]};
  for (int k = 0; k < 1024; k++) {
    const float w = W2[k * 256 + n];
#pragma unroll
    for (int r = 0; r < 4; r++) acc[r] += xr[r][k] * w;
  }
#pragma unroll
  for (int r = 0; r < 4; r++) h2[(r0 + r) * 256 + n] = fmaxf(acc[r], 0.f);
}

__global__ void fcl3_k(const float* __restrict__ h2, const float* __restrict__ W3,
                       const float* __restrict__ b3, float* __restrict__ ms) {
  __shared__ float w[256];
  w[threadIdx.x] = W3[threadIdx.x];
  __syncthreads();
  const int r = threadIdx.x;
  float s = b3[0];
  for (int k = 0; k < 256; k++) s += h2[r * 256 + k] * w[k];
  ms[r] = 1.f / (1.f + expf(-s));
}

__global__ void upsample_k(const float* __restrict__ ms, float* __restrict__ mask) {
  const int idx = blockIdx.x * 256 + threadIdx.x;
  if (idx >= 2 * 16 * IHW * IHW) return;
  const int w = idx % IHW;
  const int h = (idx / IHW) % IHW;
  const int t = (idx / (IHW * IHW)) % 16;
  const int b = idx / (16 * IHW * IHW);

  const float tf = t * 0.5f - 0.25f;
  const float hf = (h + 0.5f) * (1.f / 56.f) - 0.5f;
  const float wf = (w + 0.5f) * (1.f / 56.f) - 0.5f;

  int t0 = (int)floorf(tf); const float ft = tf - t0;
  int h0 = (int)floorf(hf); const float fh = hf - h0;
  int w0 = (int)floorf(wf); const float fw = wf - w0;
  const int t1 = min(t0 + 1, 7); t0 = max(t0, 0);
  const int h1 = min(h0 + 1, 3); h0 = max(h0, 0);
  const int w1 = min(w0 + 1, 3); w0 = max(w0, 0);

  const float* p = ms + b * 128;
  auto at = [&](int tt, int hh, int ww) { return p[(tt * 4 + hh) * 4 + ww]; };
  const float c00 = at(t0, h0, w0) * (1.f - fw) + at(t0, h0, w1) * fw;
  const float c01 = at(t0, h1, w0) * (1.f - fw) + at(t0, h1, w1) * fw;
  const float c10 = at(t1, h0, w0) * (1.f - fw) + at(t1, h0, w1) * fw;
  const float c11 = at(t1, h1, w0) * (1.f - fw) + at(t1, h1, w1) * fw;
  const float c0 = c00 * (1.f - fh) + c01 * fh;
  const float c1 = c10 * (1.f - fh) + c11 * fh;
  mask[idx] = c0 * (1.f - ft) + c1 * ft;
}

// masked[head][b][c][t][hw] = rgbs*m + bg*(1-m) -> bf16; head1 uses 1-m. Both heads in one launch.
__global__ void masking_k(const float* __restrict__ rgbs, const float* __restrict__ mask,
                          const float* __restrict__ bg, ushort* __restrict__ out) {
  const int v = blockIdx.x * 256 + threadIdx.x;
  if (v >= 2408448) return;                 // 2 heads * 1204224 float4-units
  const int head = v / 1204224;
  const int vv = v - head * 1204224;
  const int hw4 = vv % 12544;
  const int rest = vv / 12544;
  const int t = rest & 15;
  const int bc = rest >> 4;
  const int c = bc % 3;
  const int b = bc / 3;
  const float4 rg = reinterpret_cast<const float4*>(rgbs)[vv];
  float4 mk = reinterpret_cast<const float4*>(mask)[(b * 16 + t) * 12544 + hw4];
  if (head) { mk.x = 1.f - mk.x; mk.y = 1.f - mk.y; mk.z = 1.f - mk.z; mk.w = 1.f - mk.w; }
  const float4 bgv = reinterpret_cast<const float4*>(bg)[c * 12544 + hw4];
  ushort4 o;
  o.x = f2bf(rg.x * mk.x + bgv.x * (1.f - mk.x));
  o.y = f2bf(rg.y * mk.y + bgv.y * (1.f - mk.y));
  o.z = f2bf(rg.z * mk.z + bgv.z * (1.f - mk.z));
  o.w = f2bf(rg.w * mk.w + bgv.w * (1.f - mk.w));
  reinterpret_cast<ushort4*>(out)[v] = o;
}

// fused maxpool + spatial sum (bf16 in): one block per (head,b,oc,t) = 2048
__global__ __launch_bounds__(256) void pool_sum_k(const ushort* __restrict__ in,
                                                  float* __restrict__ psums) {
  const int blk = blockIdx.x;
  const ushort* p = in + (size_t)blk * (HO * HO);
  float s = 0.f;
  for (int idx = threadIdx.x; idx < PO * PO; idx += 256) {
    const int ho = idx / PO, wo = idx % PO;
    ushort m = 0;
    for (int dh = 0; dh < 3; dh++) {
      const int ih = 2 * ho + dh;
      if (ih >= HO) break;
      for (int dw = 0; dw < 3; dw++) {
        const int iw = 2 * wo + dw;
        if (iw >= HO) break;
        const ushort v = p[ih * HO + iw];
        m = (v > m) ? v : m;
      }
    }
    s += bf2f(m);
  }
  __shared__ float red[256];
  red[threadIdx.x] = s;
  __syncthreads();
  for (int off = 128; off > 0; off >>= 1) {
    if (threadIdx.x < off) red[threadIdx.x] += red[threadIdx.x + off];
    __syncthreads();
  }
  if (threadIdx.x == 0) psums[blk] = red[0];
}

// out[b_full*400 + l], b_full = head*2+b in [0,4)
__global__ void logits_k(const float* __restrict__ psums, const float* __restrict__ Wl,
                         const float* __restrict__ bl, float* __restrict__ out) {
  const int idx = blockIdx.x * 256 + threadIdx.x;
  if (idx >= 1600) return;
  const int bf = idx / 400, l = idx % 400;
  float s = bl[l];
  for (int oc = 0; oc < 64; oc++) {
    float ps = 0.f;
    for (int t = 0; t < 8; t++) ps += psums[(bf * 64 + oc) * 8 + t];
    s += (ps * (1.f / 25088.f)) * Wl[oc * 400 + l];
  }
  out[idx] = s;
}

extern "C" void kernel_launch(void* const* d_in, const int* in_sizes, int n_in,
                              void* d_out, int out_size, void* d_ws, size_t ws_size,
                              hipStream_t stream) {
  const float* rgbs   = (const float*)d_in[0];
  const float* flows  = (const float*)d_in[1];
  const float* bg     = (const float*)d_in[2];
  const float* w_rgb  = (const float*)d_in[3];
  const float* w_flow = (const float*)d_in[4];
  const float* w_feat = (const float*)d_in[5];
  const float* W1     = (const float*)d_in[6];
  const float* b1     = (const float*)d_in[7];
  const float* W2     = (const float*)d_in[8];
  const float* b2     = (const float*)d_in[9];
  const float* W3     = (const float*)d_in[10];
  const float* b3     = (const float*)d_in[11];
  const float* Wl     = (const float*)d_in[12];
  const float* bl     = (const float*)d_in[13];
  float* out = (float*)d_out;

  float* ws = (float*)d_ws;
  // A [0, 12845056)f: convbuf (2x for merged feature convs; mask stems use first half)
  //                   part (7.34M ush) aliases A — disjoint in time
  ushort* convbuf = (ushort*)ws;                    // up to 25,690,112 ush
  ushort* part    = (ushort*)ws;                    // 7,340,032 ush
  // B [12845056, 16056320)f : X
  ushort* X       = (ushort*)(ws + 12845056);       // 6,422,528 ush
  // C [16056320, ...)f : rgbsB+flowsB (die after stems), masked (2 heads) aliases
  ushort* rgbsB   = (ushort*)(ws + 16056320);       // 4,816,896 ush
  ushort* flowsB  = (ushort*)(ws + 18464768);       // 3,211,264 ush
  ushort* masked  = (ushort*)(ws + 16056320);       // 9,633,792 ush (2 heads)
  // tail at 21000000f
  float*  h1      = ws + 21000000;                  // 262,144
  float*  h2      = h1 + 262144;                    // 65,536
  float*  msmall  = h2 + 65536;                     // 256
  float*  psums   = msmall + 256;                   // 2048
  ushort* wrgb_b  = (ushort*)(psums + 2048);        // 71,680 ush
  ushort* wflow_b = wrgb_b + 71680;                 // 57,344 ush
  ushort* wfeat_b = wflow_b + 57344;                // 71,680 ush

  float* mask_full = out + 1600;

  // --- input/weight bf16 prep ---
  cvt_bf16<<<(1204224 + 255) / 256, 256, 0, stream>>>(rgbs, rgbsB, 1204224);
  cvt_bf16<<<(802816 + 255) / 256, 256, 0, stream>>>(flows, flowsB, 802816);
  wprep<3><<<(64 * 7 * 160 + 255) / 256, 256, 0, stream>>>(w_rgb, wrgb_b);
  wprep<2><<<(64 * 7 * 128 + 255) / 256, 256, 0, stream>>>(w_flow, wflow_b);
  wprep<3><<<(64 * 7 * 160 + 255) / 256, 256, 0, stream>>>(w_feat, wfeat_b);

  // --- mask branch stems ---
  conv_mfma<3><<<dim3(224, 8, 2), 256, 0, stream>>>(rgbsB, wrgb_b, convbuf);
  maxpool_gather<<<(3211264 + 255) / 256, 256, 0, stream>>>(convbuf, X, 0);
  conv_mfma<2><<<dim3(224, 8, 2), 256, 0, stream>>>(flowsB, wflow_b, convbuf);
  maxpool_gather<<<(3211264 + 255) / 256, 256, 0, stream>>>(convbuf, X, 12544);

  fcl1_mfma<<<dim3(8, 28), 512, 0, stream>>>(X, W1, part);
  h1_reduce<<<128, 256, 0, stream>>>(part, b1, h1);
  fcl2_k<<<64, 256, 0, stream>>>(h1, W2, b2, h2);
  fcl3_k<<<1, 256, 0, stream>>>(h2, W3, b3, msmall);
  upsample_k<<<(1605632 + 255) / 256, 256, 0, stream>>>(msmall, mask_full);

  // --- both feature heads merged ---
  masking_k<<<(2408448 + 255) / 256, 256, 0, stream>>>(rgbs, mask_full, bg, masked);
  conv_mfma<3><<<dim3(224, 8, 4), 256, 0, stream>>>(masked, wfeat_b, convbuf);
  pool_sum_k<<<2048, 256, 0, stream>>>(convbuf, psums);
  logits_k<<<7, 256, 0, stream>>>(psums, Wl, bl, out);
}